// Round 10
// baseline (825.226 us; speedup 1.0000x reference)
//
#include <hip/hip_runtime.h>
#include <hip/hip_bf16.h>

#define M_TOTAL 65536
#define NPTS    16384
#define CDIM    256
#define KNN     16
#define HDIM    512
#define CSTR    136   // c_lds row stride in shorts (272B, 16B-aligned)

typedef __bf16 bf16x8 __attribute__((ext_vector_type(8)));
typedef float  f32x4  __attribute__((ext_vector_type(4)));

__device__ inline float b2f(unsigned u) {
    union { unsigned v; float f; } x; x.v = u << 16; return x.f;
}
__device__ inline short fb(float f) {
    __hip_bfloat16 h = __float2bfloat16(f);
    short s; __builtin_memcpy(&s, &h, 2); return s;
}
__device__ inline unsigned pkbf(float a, float b) {
    __hip_bfloat162 h = __float22bfloat162_rn(make_float2(a, b));
    unsigned u; __builtin_memcpy(&u, &h, 4); return u;
}
__device__ inline void gload_lds16(const void* g, void* l) {
    __builtin_amdgcn_global_load_lds(
        (const __attribute__((address_space(1))) unsigned*)g,
        (__attribute__((address_space(3))) unsigned*)l, 16, 0, 0);
}
__device__ inline float gelu_tanh(float u) {
    const float t = u * (0.7978845608f + 0.0356774081f * u * u);
    const float e = __expf(2.f * t);
    const float th = 1.f - 2.f * __builtin_amdgcn_rcpf(e + 1.f);
    return 0.5f * u * (1.f + th);
}
__device__ inline void fmax8(uint4 v, float* mx) {
    mx[0] = fmaxf(mx[0], b2f(v.x & 0xffffu)); mx[1] = fmaxf(mx[1], b2f(v.x >> 16));
    mx[2] = fmaxf(mx[2], b2f(v.y & 0xffffu)); mx[3] = fmaxf(mx[3], b2f(v.y >> 16));
    mx[4] = fmaxf(mx[4], b2f(v.z & 0xffffu)); mx[5] = fmaxf(mx[5], b2f(v.z >> 16));
    mx[6] = fmaxf(mx[6], b2f(v.w & 0xffffu)); mx[7] = fmaxf(mx[7], b2f(v.w >> 16));
}

// ---------------------------------------------------------------------------
// NT GEMM: C[M][N] = A[M][K] * BT[N][K]^T, bf16 in/out, 128x256 tile, BK=64,
// 8 waves (512 thr), wave tile 64x64 (acc 4x4 = 64 VGPR). Single-buffered
// 2-barrier K-loop (R8 structure — dbuf regressed, m99-style). Swizzled
// source + XOR ds_read (conflict-free). Two-phase c_lds epilogue (48KB union).
// MODE 0: plain   MODE 1: +bias, GELU   MODE 2: + BN partials
// ---------------------------------------------------------------------------
template<int MODE>
__global__ __launch_bounds__(512, 4) void gemm_nt(
    const short* __restrict__ A, const short* __restrict__ BT,
    short* __restrict__ outB,
    const float* __restrict__ bias, float2* __restrict__ partials,
    int N, int K)
{
    __shared__ float s_sum[256], s_sq[256];
    __shared__ __align__(1024) char smem[49152];   // A 16KB + B 32KB
    short* a_lds = (short*)smem;                   // [128][64]
    short* b_lds = (short*)(smem + 16384);         // [256][64]
    short* c_lds = (short*)smem;                   // epilogue reuse [128][CSTR]

    const int tid = threadIdx.x;
    const int nx = gridDim.x, nwg = nx * gridDim.y;
    const int bid = blockIdx.y * nx + blockIdx.x;
    const int lid = (bid & 7) * (nwg >> 3) + (bid >> 3);
    const int m0 = (lid / nx) * 128, n0 = (lid % nx) * 256;

    const int w = tid >> 6, l = tid & 63;
    const int wm = w >> 2, wn = w & 3;         // 2M x 4N waves

    if (MODE == 2 && tid < 256) { s_sum[tid] = 0.f; s_sq[tid] = 0.f; }

    f32x4 acc[4][4] = {};

    const int lrow = l & 15;
    const int lkb  = (l >> 4) * 16;            // frag col byte (pre-swizzle)
    const int swz  = (lrow & 7) << 4;          // read-side XOR
    const int gr8 = l >> 3;                    // row within 8-row chunk
    const int gcs = 8 * ((l & 7) ^ gr8);       // inverse-swizzled source col

    const int nkt = K >> 6;
    for (int kt = 0; kt < nkt; ++kt) {
        const int k0 = kt << 6;
        if (kt) __syncthreads();               // all waves done reading prev
#pragma unroll
        for (int c = 0; c < 2; ++c) {          // A: 16 chunks / 8 waves
            const int q = w * 2 + c;
            gload_lds16(A + (size_t)(m0 + q * 8 + gr8) * K + k0 + gcs,
                        a_lds + q * 512 + l * 8);
        }
#pragma unroll
        for (int c = 0; c < 4; ++c) {          // B: 32 chunks / 8 waves
            const int q = w * 4 + c;
            gload_lds16(BT + (size_t)(n0 + q * 8 + gr8) * K + k0 + gcs,
                        b_lds + q * 512 + l * 8);
        }
        __syncthreads();                       // vm+lgkm drained by barrier

#pragma unroll
        for (int ks = 0; ks < 2; ++ks) {
            const int cols = ((ks * 64 + lkb) ^ swz) >> 1;   // shorts
            bf16x8 af[4], bfr[4];
#pragma unroll
            for (int i = 0; i < 4; ++i)
                af[i] = *(const bf16x8*)(a_lds + (wm * 64 + i * 16 + lrow) * 64 + cols);
#pragma unroll
            for (int j = 0; j < 4; ++j)
                bfr[j] = *(const bf16x8*)(b_lds + (wn * 64 + j * 16 + lrow) * 64 + cols);
#pragma unroll
            for (int i = 0; i < 4; ++i)
#pragma unroll
                for (int j = 0; j < 4; ++j)
                    acc[i][j] = __builtin_amdgcn_mfma_f32_16x16x32_bf16(
                        af[i], bfr[j], acc[i][j], 0, 0, 0);
        }
    }

    __syncthreads();   // all reads of a/b_lds done before c_lds reuse

    // two-phase epilogue: half h holds cols [h*128, h*128+128)
    const int lq = l >> 4;
#pragma unroll
    for (int h = 0; h < 2; ++h) {
        if ((wn >> 1) == h) {
#pragma unroll
            for (int j = 0; j < 4; ++j) {
                const int cl  = wn * 64 + j * 16 + lrow;       // 0..255
                const int clh = (wn & 1) * 64 + j * 16 + lrow; // within half
                const float bsv = (MODE == 1) ? bias[n0 + cl] : 0.f;
                float psum = 0.f, psq = 0.f;
#pragma unroll
                for (int i = 0; i < 4; ++i) {
#pragma unroll
                    for (int r = 0; r < 4; ++r) {
                        const int row = wm * 64 + i * 16 + lq * 4 + r;
                        float v = acc[i][j][r];
                        if (MODE == 1) v = gelu_tanh(v + bsv);
                        c_lds[row * CSTR + clh] = fb(v);
                        if (MODE == 2) { psum += v; psq += v * v; }
                    }
                }
                if (MODE == 2) {
                    atomicAdd(&s_sum[cl], psum);
                    atomicAdd(&s_sq[cl], psq);
                }
            }
        }
        __syncthreads();
#pragma unroll
        for (int it = 0; it < 4; ++it) {       // store half: 128x128 shorts
            const int idx = it * 512 + tid;
            const int row = idx >> 4, ch = idx & 15;
            const uint4 vv = *(const uint4*)&c_lds[row * CSTR + ch * 8];
            *(uint4*)&outB[(size_t)(m0 + row) * N + n0 + h * 128 + ch * 8] = vv;
        }
        __syncthreads();
    }
    if (MODE == 2 && tid < 256)
        partials[(size_t)(m0 >> 7) * N + n0 + tid] =
            make_float2(s_sum[tid], s_sq[tid]);
}

// ---------------------------------------------------------------------------
// LFP gather-max (R4 structure — random-line-rate wall, accepted).
// ---------------------------------------------------------------------------
__global__ __launch_bounds__(256) void gather_max(
    const short* __restrict__ p, const int* __restrict__ knn,
    short* __restrict__ yout, float2* __restrict__ partials)
{
    __shared__ float s_sum[256], s_sq[256];
    const int tid = threadIdx.x, w = tid >> 6, l = tid & 63;
    s_sum[tid] = 0.f; s_sq[tid] = 0.f;
    __syncthreads();

    const int xcd = blockIdx.x & 7, hi = blockIdx.x >> 3;
    const int gblk = (xcd >> 1) * 512 + (hi << 1) + (xcd & 1);

    const int sub = l >> 5;
    const int cl8 = (l & 31) * 8;

    float sa[8] = {}, qa[8] = {};
    for (int it = 0; it < 4; ++it) {
        const size_t g = (size_t)gblk * 32 + w * 8 + it * 2 + sub;
        const int b = (int)(g >> 14);
        const int4* kp4 = (const int4*)(knn) + g * 4;
        const int4 k0 = kp4[0], k1 = kp4[1], k2 = kp4[2], k3 = kp4[3];
        int idxs[16];
        idxs[0]=k0.x; idxs[1]=k0.y; idxs[2]=k0.z; idxs[3]=k0.w;
        idxs[4]=k1.x; idxs[5]=k1.y; idxs[6]=k1.z; idxs[7]=k1.w;
        idxs[8]=k2.x; idxs[9]=k2.y; idxs[10]=k2.z; idxs[11]=k2.w;
        idxs[12]=k3.x; idxs[13]=k3.y; idxs[14]=k3.z; idxs[15]=k3.w;
        const short* pb = p + (size_t)b * NPTS * CDIM + cl8;
        uint4 v[16];
#pragma unroll
        for (int k = 0; k < 16; ++k)
            v[k] = *(const uint4*)(pb + (size_t)idxs[k] * CDIM);
        const uint4 sv = *(const uint4*)(p + g * CDIM + cl8);

        float mx[8] = {-1e30f,-1e30f,-1e30f,-1e30f,-1e30f,-1e30f,-1e30f,-1e30f};
#pragma unroll
        for (int k = 0; k < 16; ++k) fmax8(v[k], mx);

        float t[8];
        t[0] = mx[0] - b2f(sv.x & 0xffffu); t[1] = mx[1] - b2f(sv.x >> 16);
        t[2] = mx[2] - b2f(sv.y & 0xffffu); t[3] = mx[3] - b2f(sv.y >> 16);
        t[4] = mx[4] - b2f(sv.z & 0xffffu); t[5] = mx[5] - b2f(sv.z >> 16);
        t[6] = mx[6] - b2f(sv.w & 0xffffu); t[7] = mx[7] - b2f(sv.w >> 16);

        uint4 pk;
        pk.x = pkbf(t[0], t[1]);
        pk.y = pkbf(t[2], t[3]);
        pk.z = pkbf(t[4], t[5]);
        pk.w = pkbf(t[6], t[7]);
        *(uint4*)(yout + g * CDIM + cl8) = pk;
#pragma unroll
        for (int j = 0; j < 8; ++j) { sa[j] += t[j]; qa[j] += t[j] * t[j]; }
    }
#pragma unroll
    for (int j = 0; j < 8; ++j) {
        atomicAdd(&s_sum[cl8 + j], sa[j]);
        atomicAdd(&s_sq[cl8 + j], qa[j]);
    }
    __syncthreads();
    partials[(size_t)gblk * CDIM + tid] = make_float2(s_sum[tid], s_sq[tid]);
}

// ---------------------------------------------------------------------------
// stats reduce — one dispatch. Block = channel; threads stride rows.
// ---------------------------------------------------------------------------
__global__ __launch_bounds__(256) void reduce_stats(
    const float2* __restrict__ partials, int nblk,
    const float* __restrict__ bnw, const float* __restrict__ bnb,
    float2* __restrict__ scsh)
{
    __shared__ float ss[4], qq[4];
    const int c = blockIdx.x, tid = threadIdx.x, w = tid >> 6, l = tid & 63;
    float s = 0.f, q = 0.f;
    for (int rb = tid; rb < nblk; rb += 256) {
        const float2 v = partials[(size_t)rb * CDIM + c];
        s += v.x; q += v.y;
    }
#pragma unroll
    for (int off = 32; off > 0; off >>= 1) {
        s += __shfl_down(s, off);
        q += __shfl_down(q, off);
    }
    if (l == 0) { ss[w] = s; qq[w] = q; }
    __syncthreads();
    if (tid == 0) {
        const float S = ss[0] + ss[1] + ss[2] + ss[3];
        const float Q = qq[0] + qq[1] + qq[2] + qq[3];
        const float invM = 1.f / 65536.f;
        const float mean = S * invM;
        const float var  = Q * invM - mean * mean;
        const float istd = rsqrtf(var + 1e-5f);
        const float sc   = bnw[c] * istd;
        scsh[c] = make_float2(sc, bnb[c] - mean * sc);
    }
}

// ---------------------------------------------------------------------------
// bn+residual, bf16 chain. 8 elems/thread.
// V0: resid bf16 -> out bf16 | V1: resid f32 -> out bf16 | V2: resid bf16 -> out f32
// ---------------------------------------------------------------------------
template<int V>
__global__ __launch_bounds__(256) void bn_residual(
    const short* __restrict__ y, const short* __restrict__ xb_in,
    const float* __restrict__ xf_in, const float2* __restrict__ scsh,
    short* __restrict__ xb_out, float* __restrict__ xf_out)
{
    const size_t t = (size_t)blockIdx.x * 256 + threadIdx.x;
    const uint4 yv = ((const uint4*)y)[t];
    float xr[8];
    if (V == 1) {
        const float4 a = ((const float4*)xf_in)[2 * t];
        const float4 b = ((const float4*)xf_in)[2 * t + 1];
        xr[0]=a.x; xr[1]=a.y; xr[2]=a.z; xr[3]=a.w;
        xr[4]=b.x; xr[5]=b.y; xr[6]=b.z; xr[7]=b.w;
    } else {
        const uint4 xv = ((const uint4*)xb_in)[t];
        xr[0]=b2f(xv.x & 0xffffu); xr[1]=b2f(xv.x >> 16);
        xr[2]=b2f(xv.y & 0xffffu); xr[3]=b2f(xv.y >> 16);
        xr[4]=b2f(xv.z & 0xffffu); xr[5]=b2f(xv.z >> 16);
        xr[6]=b2f(xv.w & 0xffffu); xr[7]=b2f(xv.w >> 16);
    }
    float yr[8];
    yr[0]=b2f(yv.x & 0xffffu); yr[1]=b2f(yv.x >> 16);
    yr[2]=b2f(yv.y & 0xffffu); yr[3]=b2f(yv.y >> 16);
    yr[4]=b2f(yv.z & 0xffffu); yr[5]=b2f(yv.z >> 16);
    yr[6]=b2f(yv.w & 0xffffu); yr[7]=b2f(yv.w >> 16);

    const int c0 = (int)((t * 8) & (CDIM - 1));
    float o[8];
#pragma unroll
    for (int j = 0; j < 8; ++j) {
        const float2 sc = scsh[c0 + j];
        o[j] = xr[j] + yr[j] * sc.x + sc.y;
    }
    if (V == 2) {
        ((float4*)xf_out)[2 * t]     = make_float4(o[0], o[1], o[2], o[3]);
        ((float4*)xf_out)[2 * t + 1] = make_float4(o[4], o[5], o[6], o[7]);
    } else {
        uint4 pk;
        pk.x = pkbf(o[0], o[1]);
        pk.y = pkbf(o[2], o[3]);
        pk.z = pkbf(o[4], o[5]);
        pk.w = pkbf(o[6], o[7]);
        ((uint4*)xb_out)[t] = pk;
    }
}

__global__ __launch_bounds__(256) void cast_x(
    const float* __restrict__ x, short* __restrict__ xb)
{
    const size_t t = (size_t)blockIdx.x * 256 + threadIdx.x;
    const float4 v = ((const float4*)x)[t];
    uint2 pk;
    pk.x = pkbf(v.x, v.y);
    pk.y = pkbf(v.z, v.w);
    ((uint2*)xb)[t] = pk;
}

__global__ __launch_bounds__(256) void transpose_cast(
    const float* __restrict__ src, short* __restrict__ dst, int R, int Cc)
{
    const size_t base = (size_t)blockIdx.y * R * Cc;
    const int i = blockIdx.x * 256 + threadIdx.x;
    if (i < R * Cc) {
        const int r = i / Cc, c = i % Cc;
        dst[base + (size_t)c * R + r] = fb(src[base + i]);
    }
}

// ---------------------------------------------------------------------------

extern "C" void kernel_launch(void* const* d_in, const int* in_sizes, int n_in,
                              void* d_out, int out_size, void* d_ws, size_t ws_size,
                              hipStream_t stream)
{
    (void)in_sizes; (void)n_in; (void)out_size; (void)ws_size;

    const float* x_in      = (const float*)d_in[0];
    const int*   knn       = (const int*)  d_in[1];
    const float* lfp_w     = (const float*)d_in[2];
    const float* lfp_bn_w  = (const float*)d_in[3];
    const float* lfp_bn_b  = (const float*)d_in[4];
    const float* mlp0_w1   = (const float*)d_in[5];
    const float* mlp0_b1   = (const float*)d_in[6];
    const float* mlp0_w2   = (const float*)d_in[7];
    const float* mlp0_bn_w = (const float*)d_in[8];
    const float* mlp0_bn_b = (const float*)d_in[9];
    const float* mlps_w1   = (const float*)d_in[10];
    const float* mlps_b1   = (const float*)d_in[11];
    const float* mlps_w2   = (const float*)d_in[12];
    const float* mlps_bn_w = (const float*)d_in[13];
    const float* mlps_bn_b = (const float*)d_in[14];

    char* ws = (char*)d_ws;
    short*  xb       = (short*) (ws + 0);                    // 32 MB
    short*  ybB      = (short*) (ws + 33554432ull);          // 32 MB
    short*  hp       = (short*) (ws + 67108864ull);          // 64 MB (h / p)
    float2* partials = (float2*)(ws + 134217728ull);         //  4 MB
    float2* scsh     = (float2*)(ws + 138444800ull);         //  2 KB
    short*  lfpWT    = (short*) (ws + 138446848ull);         // 512 KB
    short*  w1T0     = (short*) (ws + 138971136ull);         // 256 KB
    short*  w2T0     = (short*) (ws + 139233280ull);         // 256 KB
    short*  w1Ts     = (short*) (ws + 139495424ull);         // 512 KB
    short*  w2Ts     = (short*) (ws + 140019712ull);         // 512 KB
    float*  xout     = (float*)d_out;

    const dim3 blk(256);
    const dim3 blkG(512);

    transpose_cast<<<dim3(256, 4), blk, 0, stream>>>(lfp_w,   lfpWT, 256, 256);
    transpose_cast<<<dim3(512, 1), blk, 0, stream>>>(mlp0_w1, w1T0,  256, 512);
    transpose_cast<<<dim3(512, 1), blk, 0, stream>>>(mlp0_w2, w2T0,  512, 256);
    transpose_cast<<<dim3(512, 2), blk, 0, stream>>>(mlps_w1, w1Ts,  256, 512);
    transpose_cast<<<dim3(512, 2), blk, 0, stream>>>(mlps_w2, w2Ts,  512, 256);
    cast_x<<<16384, blk, 0, stream>>>(x_in, xb);

    auto run_mlp = [&](const short* w1T, const float* b1, const short* w2T,
                       const float* bnw, const float* bnb, int variant) {
        gemm_nt<1><<<dim3(2, 512), blkG, 0, stream>>>(xb, w1T, hp,  b1, nullptr, 512, 256);
        gemm_nt<2><<<dim3(1, 512), blkG, 0, stream>>>(hp, w2T, ybB, nullptr, partials, 256, 512);
        reduce_stats<<<256, blk, 0, stream>>>(partials, 512, bnw, bnb, scsh);
        if (variant == 1)
            bn_residual<1><<<8192, blk, 0, stream>>>(ybB, nullptr, x_in, scsh, xb, nullptr);
        else if (variant == 2)
            bn_residual<2><<<8192, blk, 0, stream>>>(ybB, xb, nullptr, scsh, nullptr, xout);
        else
            bn_residual<0><<<8192, blk, 0, stream>>>(ybB, xb, nullptr, scsh, xb, nullptr);
    };

    run_mlp(w1T0, mlp0_b1, w2T0, mlp0_bn_w, mlp0_bn_b, 1);

    for (int i = 0; i < 4; ++i) {
        gemm_nt<0><<<dim3(1, 512), blkG, 0, stream>>>(xb, lfpWT + (size_t)i * 65536,
                                                      hp, nullptr, nullptr, 256, 256);
        gather_max<<<2048, blk, 0, stream>>>(hp, knn, ybB, partials);
        reduce_stats<<<256, blk, 0, stream>>>(partials, 2048,
                                              lfp_bn_w + i * 256, lfp_bn_b + i * 256, scsh);
        bn_residual<0><<<8192, blk, 0, stream>>>(ybB, xb, nullptr, scsh, xb, nullptr);
        if (i & 1) {
            const int j = i >> 1;
            run_mlp(w1Ts + (size_t)j * 131072, mlps_b1 + j * 512,
                    w2Ts + (size_t)j * 131072,
                    mlps_bn_w + j * 256, mlps_bn_b + j * 256,
                    (i == 3) ? 2 : 0);
        }
    }
}

// Round 11
// 771.826 us; speedup vs baseline: 1.0692x; 1.0692x over previous
//
#include <hip/hip_runtime.h>
#include <hip/hip_bf16.h>

#define M_TOTAL 65536
#define NPTS    16384
#define CDIM    256
#define KNN     16
#define HDIM    512
#define CSTR    136   // c_lds row stride in shorts (272B, 16B-aligned)

typedef __bf16 bf16x8 __attribute__((ext_vector_type(8)));
typedef float  f32x4  __attribute__((ext_vector_type(4)));

__device__ inline float b2f(unsigned u) {
    union { unsigned v; float f; } x; x.v = u << 16; return x.f;
}
__device__ inline short fb(float f) {
    __hip_bfloat16 h = __float2bfloat16(f);
    short s; __builtin_memcpy(&s, &h, 2); return s;
}
__device__ inline unsigned pkbf(float a, float b) {
    __hip_bfloat162 h = __float22bfloat162_rn(make_float2(a, b));
    unsigned u; __builtin_memcpy(&u, &h, 4); return u;
}
__device__ inline void gload_lds16(const void* g, void* l) {
    __builtin_amdgcn_global_load_lds(
        (const __attribute__((address_space(1))) unsigned*)g,
        (__attribute__((address_space(3))) unsigned*)l, 16, 0, 0);
}
__device__ inline float gelu_tanh(float u) {
    const float t = u * (0.7978845608f + 0.0356774081f * u * u);
    const float e = __expf(2.f * t);
    const float th = 1.f - 2.f * __builtin_amdgcn_rcpf(e + 1.f);
    return 0.5f * u * (1.f + th);
}
__device__ inline void fmax8(uint4 v, float* mx) {
    mx[0] = fmaxf(mx[0], b2f(v.x & 0xffffu)); mx[1] = fmaxf(mx[1], b2f(v.x >> 16));
    mx[2] = fmaxf(mx[2], b2f(v.y & 0xffffu)); mx[3] = fmaxf(mx[3], b2f(v.y >> 16));
    mx[4] = fmaxf(mx[4], b2f(v.z & 0xffffu)); mx[5] = fmaxf(mx[5], b2f(v.z >> 16));
    mx[6] = fmaxf(mx[6], b2f(v.w & 0xffffu)); mx[7] = fmaxf(mx[7], b2f(v.w >> 16));
}

// ---------------------------------------------------------------------------
// NT GEMM (R8 structure — best measured): 128x128 tile, BK=64, 4 waves,
// single-buffered 2-barrier K-loop, swizzled-source global_load_lds +
// XOR ds_read (conflict-free), c_lds epilogue unions over a/b_lds.
// MODE 0: plain   MODE 1: +bias, GELU   MODE 2: + BN partials
// ---------------------------------------------------------------------------
template<int MODE>
__global__ __launch_bounds__(256) void gemm_nt(
    const short* __restrict__ A, const short* __restrict__ BT,
    short* __restrict__ outB,
    const float* __restrict__ bias, float2* __restrict__ partials,
    int N, int K)
{
    __shared__ float s_sum[128], s_sq[128];
    __shared__ __align__(1024) char smem[34816];   // max(2*16KB, 128*CSTR*2)
    short* a_lds = (short*)smem;            // [128][64] (col-swizzled), 16KB
    short* b_lds = (short*)(smem + 16384);  // 16KB
    short* c_lds = (short*)smem;            // epilogue reuse, [128][CSTR]

    const int tid = threadIdx.x;
    const int nx = gridDim.x, nwg = nx * gridDim.y;
    const int bid = blockIdx.y * nx + blockIdx.x;
    const int lid = (bid & 7) * (nwg >> 3) + (bid >> 3);
    const int m0 = (lid / nx) * 128, n0 = (lid % nx) * 128;

    const int w = tid >> 6, l = tid & 63;
    const int wm = w >> 1, wn = w & 1;

    if (MODE == 2 && tid < 128) { s_sum[tid] = 0.f; s_sq[tid] = 0.f; }

    f32x4 acc[4][4] = {};

    const int lrow = l & 15;
    const int lkb  = (l >> 4) * 16;            // frag col byte (pre-swizzle)
    const int swz  = (lrow & 7) << 4;          // read-side XOR
    const int gr8 = l >> 3;                    // row within chunk
    const int gcs = 8 * ((l & 7) ^ gr8);       // source col (shorts)

    const int nkt = K >> 6;
    for (int kt = 0; kt < nkt; ++kt) {
        const int k0 = kt << 6;
        if (kt) __syncthreads();
#pragma unroll
        for (int c = 0; c < 4; ++c) {
            const int q = w * 4 + c;
            gload_lds16(A  + (size_t)(m0 + q * 8 + gr8) * K + k0 + gcs,
                        a_lds + q * 512 + l * 8);
            gload_lds16(BT + (size_t)(n0 + q * 8 + gr8) * K + k0 + gcs,
                        b_lds + q * 512 + l * 8);
        }
        __syncthreads();

#pragma unroll
        for (int ks = 0; ks < 2; ++ks) {
            const int cols = ((ks * 64 + lkb) ^ swz) >> 1;   // shorts
            bf16x8 af[4], bfr[4];
#pragma unroll
            for (int i = 0; i < 4; ++i)
                af[i] = *(const bf16x8*)(a_lds + (wm * 64 + i * 16 + lrow) * 64 + cols);
#pragma unroll
            for (int j = 0; j < 4; ++j)
                bfr[j] = *(const bf16x8*)(b_lds + (wn * 64 + j * 16 + lrow) * 64 + cols);
#pragma unroll
            for (int i = 0; i < 4; ++i)
#pragma unroll
                for (int j = 0; j < 4; ++j)
                    acc[i][j] = __builtin_amdgcn_mfma_f32_16x16x32_bf16(
                        af[i], bfr[j], acc[i][j], 0, 0, 0);
        }
    }

    __syncthreads();   // all waves done reading a/b_lds before c_lds reuse

    const int lq = l >> 4;
#pragma unroll
    for (int j = 0; j < 4; ++j) {
        const int cl  = wn * 64 + j * 16 + lrow;
        const float bsv = (MODE == 1) ? bias[n0 + cl] : 0.f;
        float psum = 0.f, psq = 0.f;
#pragma unroll
        for (int i = 0; i < 4; ++i) {
#pragma unroll
            for (int r = 0; r < 4; ++r) {
                const int row = wm * 64 + i * 16 + lq * 4 + r;
                float v = acc[i][j][r];
                if (MODE == 1) v = gelu_tanh(v + bsv);
                c_lds[row * CSTR + cl] = fb(v);
                if (MODE == 2) { psum += v; psq += v * v; }
            }
        }
        if (MODE == 2) {
            atomicAdd(&s_sum[cl], psum);
            atomicAdd(&s_sq[cl], psq);
        }
    }
    __syncthreads();
#pragma unroll
    for (int it = 0; it < 8; ++it) {
        const int idx = it * 256 + tid;
        const int row = idx >> 4, ch = idx & 15;
        const uint4 vv = *(const uint4*)&c_lds[row * CSTR + ch * 8];
        *(uint4*)&outB[(size_t)(m0 + row) * N + n0 + ch * 8] = vv;
    }
    if (MODE == 2 && tid < 128)
        partials[(size_t)(m0 >> 7) * N + n0 + tid] =
            make_float2(s_sum[tid], s_sq[tid]);
}

// ---------------------------------------------------------------------------
// LFP gather-max (R4 structure — random-line-rate wall, accepted).
// ---------------------------------------------------------------------------
__global__ __launch_bounds__(256) void gather_max(
    const short* __restrict__ p, const int* __restrict__ knn,
    short* __restrict__ yout, float2* __restrict__ partials)
{
    __shared__ float s_sum[256], s_sq[256];
    const int tid = threadIdx.x, w = tid >> 6, l = tid & 63;
    s_sum[tid] = 0.f; s_sq[tid] = 0.f;
    __syncthreads();

    const int xcd = blockIdx.x & 7, hi = blockIdx.x >> 3;
    const int gblk = (xcd >> 1) * 512 + (hi << 1) + (xcd & 1);

    const int sub = l >> 5;
    const int cl8 = (l & 31) * 8;

    float sa[8] = {}, qa[8] = {};
    for (int it = 0; it < 4; ++it) {
        const size_t g = (size_t)gblk * 32 + w * 8 + it * 2 + sub;
        const int b = (int)(g >> 14);
        const int4* kp4 = (const int4*)(knn) + g * 4;
        const int4 k0 = kp4[0], k1 = kp4[1], k2 = kp4[2], k3 = kp4[3];
        int idxs[16];
        idxs[0]=k0.x; idxs[1]=k0.y; idxs[2]=k0.z; idxs[3]=k0.w;
        idxs[4]=k1.x; idxs[5]=k1.y; idxs[6]=k1.z; idxs[7]=k1.w;
        idxs[8]=k2.x; idxs[9]=k2.y; idxs[10]=k2.z; idxs[11]=k2.w;
        idxs[12]=k3.x; idxs[13]=k3.y; idxs[14]=k3.z; idxs[15]=k3.w;
        const short* pb = p + (size_t)b * NPTS * CDIM + cl8;
        uint4 v[16];
#pragma unroll
        for (int k = 0; k < 16; ++k)
            v[k] = *(const uint4*)(pb + (size_t)idxs[k] * CDIM);
        const uint4 sv = *(const uint4*)(p + g * CDIM + cl8);

        float mx[8] = {-1e30f,-1e30f,-1e30f,-1e30f,-1e30f,-1e30f,-1e30f,-1e30f};
#pragma unroll
        for (int k = 0; k < 16; ++k) fmax8(v[k], mx);

        float t[8];
        t[0] = mx[0] - b2f(sv.x & 0xffffu); t[1] = mx[1] - b2f(sv.x >> 16);
        t[2] = mx[2] - b2f(sv.y & 0xffffu); t[3] = mx[3] - b2f(sv.y >> 16);
        t[4] = mx[4] - b2f(sv.z & 0xffffu); t[5] = mx[5] - b2f(sv.z >> 16);
        t[6] = mx[6] - b2f(sv.w & 0xffffu); t[7] = mx[7] - b2f(sv.w >> 16);

        uint4 pk;
        pk.x = pkbf(t[0], t[1]);
        pk.y = pkbf(t[2], t[3]);
        pk.z = pkbf(t[4], t[5]);
        pk.w = pkbf(t[6], t[7]);
        *(uint4*)(yout + g * CDIM + cl8) = pk;
#pragma unroll
        for (int j = 0; j < 8; ++j) { sa[j] += t[j]; qa[j] += t[j] * t[j]; }
    }
#pragma unroll
    for (int j = 0; j < 8; ++j) {
        atomicAdd(&s_sum[cl8 + j], sa[j]);
        atomicAdd(&s_sq[cl8 + j], qa[j]);
    }
    __syncthreads();
    partials[(size_t)gblk * CDIM + tid] = make_float2(s_sum[tid], s_sq[tid]);
}

// ---------------------------------------------------------------------------
// stats reduce — one dispatch. Block = channel; threads stride rows.
// ---------------------------------------------------------------------------
__global__ __launch_bounds__(256) void reduce_stats(
    const float2* __restrict__ partials, int nblk,
    const float* __restrict__ bnw, const float* __restrict__ bnb,
    float2* __restrict__ scsh)
{
    __shared__ float ss[4], qq[4];
    const int c = blockIdx.x, tid = threadIdx.x, w = tid >> 6, l = tid & 63;
    float s = 0.f, q = 0.f;
    for (int rb = tid; rb < nblk; rb += 256) {
        const float2 v = partials[(size_t)rb * CDIM + c];
        s += v.x; q += v.y;
    }
#pragma unroll
    for (int off = 32; off > 0; off >>= 1) {
        s += __shfl_down(s, off);
        q += __shfl_down(q, off);
    }
    if (l == 0) { ss[w] = s; qq[w] = q; }
    __syncthreads();
    if (tid == 0) {
        const float S = ss[0] + ss[1] + ss[2] + ss[3];
        const float Q = qq[0] + qq[1] + qq[2] + qq[3];
        const float invM = 1.f / 65536.f;
        const float mean = S * invM;
        const float var  = Q * invM - mean * mean;
        const float istd = rsqrtf(var + 1e-5f);
        const float sc   = bnw[c] * istd;
        scsh[c] = make_float2(sc, bnb[c] - mean * sc);
    }
}

// ---------------------------------------------------------------------------
// bn+residual, bf16 chain. 8 elems/thread.
// V0: resid bf16 -> out bf16 | V1: resid f32 -> out bf16 | V2: resid bf16 -> out f32
// ---------------------------------------------------------------------------
template<int V>
__global__ __launch_bounds__(256) void bn_residual(
    const short* __restrict__ y, const short* __restrict__ xb_in,
    const float* __restrict__ xf_in, const float2* __restrict__ scsh,
    short* __restrict__ xb_out, float* __restrict__ xf_out)
{
    const size_t t = (size_t)blockIdx.x * 256 + threadIdx.x;
    const uint4 yv = ((const uint4*)y)[t];
    float xr[8];
    if (V == 1) {
        const float4 a = ((const float4*)xf_in)[2 * t];
        const float4 b = ((const float4*)xf_in)[2 * t + 1];
        xr[0]=a.x; xr[1]=a.y; xr[2]=a.z; xr[3]=a.w;
        xr[4]=b.x; xr[5]=b.y; xr[6]=b.z; xr[7]=b.w;
    } else {
        const uint4 xv = ((const uint4*)xb_in)[t];
        xr[0]=b2f(xv.x & 0xffffu); xr[1]=b2f(xv.x >> 16);
        xr[2]=b2f(xv.y & 0xffffu); xr[3]=b2f(xv.y >> 16);
        xr[4]=b2f(xv.z & 0xffffu); xr[5]=b2f(xv.z >> 16);
        xr[6]=b2f(xv.w & 0xffffu); xr[7]=b2f(xv.w >> 16);
    }
    float yr[8];
    yr[0]=b2f(yv.x & 0xffffu); yr[1]=b2f(yv.x >> 16);
    yr[2]=b2f(yv.y & 0xffffu); yr[3]=b2f(yv.y >> 16);
    yr[4]=b2f(yv.z & 0xffffu); yr[5]=b2f(yv.z >> 16);
    yr[6]=b2f(yv.w & 0xffffu); yr[7]=b2f(yv.w >> 16);

    const int c0 = (int)((t * 8) & (CDIM - 1));
    float o[8];
#pragma unroll
    for (int j = 0; j < 8; ++j) {
        const float2 sc = scsh[c0 + j];
        o[j] = xr[j] + yr[j] * sc.x + sc.y;
    }
    if (V == 2) {
        ((float4*)xf_out)[2 * t]     = make_float4(o[0], o[1], o[2], o[3]);
        ((float4*)xf_out)[2 * t + 1] = make_float4(o[4], o[5], o[6], o[7]);
    } else {
        uint4 pk;
        pk.x = pkbf(o[0], o[1]);
        pk.y = pkbf(o[2], o[3]);
        pk.z = pkbf(o[4], o[5]);
        pk.w = pkbf(o[6], o[7]);
        ((uint4*)xb_out)[t] = pk;
    }
}

// ---------------------------------------------------------------------------
// prep — ONE dispatch: cast_x (blocks 0..16383) + 5 weight transposes.
// transpose seg: i = elems within segment; batch = i/(R*C); r,c within.
// ---------------------------------------------------------------------------
__global__ __launch_bounds__(256) void prep(
    const float* __restrict__ x, short* __restrict__ xb,
    const float* __restrict__ lfp_w, short* __restrict__ lfpWT,
    const float* __restrict__ w1_0, short* __restrict__ w1T0,
    const float* __restrict__ w2_0, short* __restrict__ w2T0,
    const float* __restrict__ w1s, short* __restrict__ w1Ts,
    const float* __restrict__ w2s, short* __restrict__ w2Ts)
{
    const int tid = threadIdx.x;
    int bid = blockIdx.x;
    if (bid < 16384) {
        const size_t t = (size_t)bid * 256 + tid;
        const float4 v = ((const float4*)x)[t];
        uint2 pk;
        pk.x = pkbf(v.x, v.y);
        pk.y = pkbf(v.z, v.w);
        ((uint2*)xb)[t] = pk;
        return;
    }
    bid -= 16384;
    const float* src; short* dst; int R, Cc, nb, segblk;
    if (bid < 1024)      { src = lfp_w; dst = lfpWT; R = 256; Cc = 256; segblk = bid; }
    else if (bid < 1536) { src = w1_0;  dst = w1T0;  R = 256; Cc = 512; segblk = bid - 1024; }
    else if (bid < 2048) { src = w2_0;  dst = w2T0;  R = 512; Cc = 256; segblk = bid - 1536; }
    else if (bid < 3072) { src = w1s;   dst = w1Ts;  R = 256; Cc = 512; segblk = bid - 2048; }
    else                 { src = w2s;   dst = w2Ts;  R = 512; Cc = 256; segblk = bid - 3072; }
    const int i = segblk * 256 + tid;
    const int rc = R * Cc;
    const int batch = i / rc, rem = i - batch * rc;
    const int r = rem / Cc, c = rem - r * Cc;
    dst[(size_t)batch * rc + (size_t)c * R + r] = fb(src[(size_t)batch * rc + rem]);
}

// ---------------------------------------------------------------------------

extern "C" void kernel_launch(void* const* d_in, const int* in_sizes, int n_in,
                              void* d_out, int out_size, void* d_ws, size_t ws_size,
                              hipStream_t stream)
{
    (void)in_sizes; (void)n_in; (void)out_size; (void)ws_size;

    const float* x_in      = (const float*)d_in[0];
    const int*   knn       = (const int*)  d_in[1];
    const float* lfp_w     = (const float*)d_in[2];
    const float* lfp_bn_w  = (const float*)d_in[3];
    const float* lfp_bn_b  = (const float*)d_in[4];
    const float* mlp0_w1   = (const float*)d_in[5];
    const float* mlp0_b1   = (const float*)d_in[6];
    const float* mlp0_w2   = (const float*)d_in[7];
    const float* mlp0_bn_w = (const float*)d_in[8];
    const float* mlp0_bn_b = (const float*)d_in[9];
    const float* mlps_w1   = (const float*)d_in[10];
    const float* mlps_b1   = (const float*)d_in[11];
    const float* mlps_w2   = (const float*)d_in[12];
    const float* mlps_bn_w = (const float*)d_in[13];
    const float* mlps_bn_b = (const float*)d_in[14];

    char* ws = (char*)d_ws;
    short*  xb       = (short*) (ws + 0);                    // 32 MB
    short*  ybB      = (short*) (ws + 33554432ull);          // 32 MB
    short*  hp       = (short*) (ws + 67108864ull);          // 64 MB (h / p)
    float2* partials = (float2*)(ws + 134217728ull);         //  4 MB
    float2* scsh     = (float2*)(ws + 138444800ull);         //  2 KB
    short*  lfpWT    = (short*) (ws + 138446848ull);         // 512 KB
    short*  w1T0     = (short*) (ws + 138971136ull);         // 256 KB
    short*  w2T0     = (short*) (ws + 139233280ull);         // 256 KB
    short*  w1Ts     = (short*) (ws + 139495424ull);         // 512 KB
    short*  w2Ts     = (short*) (ws + 140019712ull);         // 512 KB
    float*  xout     = (float*)d_out;

    const dim3 blk(256);

    prep<<<16384 + 4096, blk, 0, stream>>>(x_in, xb, lfp_w, lfpWT,
                                           mlp0_w1, w1T0, mlp0_w2, w2T0,
                                           mlps_w1, w1Ts, mlps_w2, w2Ts);

    auto run_mlp = [&](const short* w1T, const float* b1, const short* w2T,
                       const float* bnw, const float* bnb, int variant) {
        gemm_nt<1><<<dim3(4, 512), blk, 0, stream>>>(xb, w1T, hp,  b1, nullptr, 512, 256);
        gemm_nt<2><<<dim3(2, 512), blk, 0, stream>>>(hp, w2T, ybB, nullptr, partials, 256, 512);
        reduce_stats<<<256, blk, 0, stream>>>(partials, 512, bnw, bnb, scsh);
        if (variant == 1)
            bn_residual<1><<<8192, blk, 0, stream>>>(ybB, nullptr, x_in, scsh, xb, nullptr);
        else if (variant == 2)
            bn_residual<2><<<8192, blk, 0, stream>>>(ybB, xb, nullptr, scsh, nullptr, xout);
        else
            bn_residual<0><<<8192, blk, 0, stream>>>(ybB, xb, nullptr, scsh, xb, nullptr);
    };

    run_mlp(w1T0, mlp0_b1, w2T0, mlp0_bn_w, mlp0_bn_b, 1);

    for (int i = 0; i < 4; ++i) {
        gemm_nt<0><<<dim3(2, 512), blk, 0, stream>>>(xb, lfpWT + (size_t)i * 65536,
                                                     hp, nullptr, nullptr, 256, 256);
        gather_max<<<2048, blk, 0, stream>>>(hp, knn, ybB, partials);
        reduce_stats<<<256, blk, 0, stream>>>(partials, 2048,
                                              lfp_bn_w + i * 256, lfp_bn_b + i * 256, scsh);
        bn_residual<0><<<8192, blk, 0, stream>>>(ybB, xb, nullptr, scsh, xb, nullptr);
        if (i & 1) {
            const int j = i >> 1;
            run_mlp(w1Ts + (size_t)j * 131072, mlps_b1 + j * 512,
                    w2Ts + (size_t)j * 131072,
                    mlps_bn_w + j * 256, mlps_bn_b + j * 256,
                    (i == 3) ? 2 : 0);
        }
    }
}